// Round 14
// baseline (50.883 us; speedup 1.0000x reference)
//
#include <hip/hip_runtime.h>
#include <hip/hip_bf16.h>

#define M_DIM 8192
#define N_DIM 8192

typedef short short8 __attribute__((ext_vector_type(8)));
typedef float f32x4 __attribute__((ext_vector_type(4)));

static __device__ __forceinline__ short f2bf(float f) {
    __hip_bfloat16 h = __float2bfloat16(f);   // RNE convert
    union { __hip_bfloat16 h; short s; } u;
    u.h = h;
    return u.s;
}

// Fused single kernel: C[m,n] = dq[m,:] @ act[:,n].
// R13 STRUCTURE (49.6 us best): grid 512 (2 blocks/CU), B fragments in
// registers built once, lockstep band M-walk, no block barriers after none,
// fire-and-forget PLAIN stores, wave owns 32 rows x 128 cols, 512B bursts.
// R14 single-variable change: XCD-CONTIGUOUS COLUMN OWNERSHIP. Dispatch is
// round-robin (XCD = blockIdx%8). Remap bn=(blockIdx%8)*8+((blockIdx/8)%8)
// so XCD x owns bn in [8x,8x+8) => its private L2's dirty C-data is a
// CONTIGUOUS 4KB span of every row (was: 512B strips at 4KB stride). Each
// XCD's eviction stream to DRAM becomes dense 4KB runs like the fill kernel.
__global__ __launch_bounds__(256, 2) void gemm_dq(const float* __restrict__ scale,
                                                  const int* __restrict__ offset,
                                                  const int* __restrict__ weight,
                                                  const float* __restrict__ act,
                                                  float* __restrict__ C) {
    // wave-private staging: 16 rows x 132 cols f32 (pad -> <=2-way conflicts)
    __shared__ float cs[4][16 * 132];

    const int tid  = threadIdx.x;
    const int lane = tid & 63;
    const int wid  = tid >> 6;
    const int l15  = lane & 15;
    const int l4   = lane >> 4;

    // XCD-contiguous remap (bijective over grid 512):
    const int xcd = (int)blockIdx.x & 7;     // HW: XCD = blockIdx % 8
    const int q   = (int)blockIdx.x >> 3;
    const int bn  = xcd * 8 + (q & 7);       // XCD owns 8 adjacent n-tiles
    const int mg  = q >> 3;                  // 8 band-slots
    const int n0  = bn * 128;                // block's 128-col extent

    // ---- B fragments: built ONCE from act [64, 8192] f32 (L2/L3-hot),
    // converted to bf16 in-register; reused across all 8 m-tiles.
    // Element j of fragment (kh,fn) = act[kh*32 + l4*8 + j][n0 + fn*16 + l15].
    short8 bfrag[2][8];
    #pragma unroll
    for (int kh = 0; kh < 2; ++kh) {
        #pragma unroll
        for (int fn = 0; fn < 8; ++fn) {
            const float* ap = act + (size_t)(kh * 32 + l4 * 8) * N_DIM + (n0 + fn * 16 + l15);
            short8 b;
            #pragma unroll
            for (int j = 0; j < 8; ++j) {
                b[j] = f2bf(ap[(size_t)j * N_DIM]);
            }
            bfrag[kh][fn] = b;
        }
    }

    float* ws = &cs[wid][0];

    #pragma unroll 2
    for (int ti = 0; ti < 8; ++ti) {
        // Lockstep bands: at step ti the whole grid writes rows
        // [ti*1024, ti*1024+1024) -- one contiguous 32 MB region.
        const int m0 = (ti * 8 + mg) * 128 + wid * 32;   // wave's 32-row slab

        // ---- Process the wave's two 16-row fragments one at a time
        // (keeps acc live-set at 32 VGPR).
        #pragma unroll
        for (int fm = 0; fm < 2; ++fm) {
            // A fragments: dequantize 4-bit weights directly into registers.
            // Lane: row m = m0+fm*16+(lane&15), k = kh*32+(lane>>4)*8+j
            // => group g = kh*4+(lane>>4): one word, one scale, one offset nibble.
            short8 afrag[2];
            #pragma unroll
            for (int kh = 0; kh < 2; ++kh) {
                const int g = kh * 4 + l4;
                const int m = m0 + fm * 16 + l15;
                const unsigned w = (unsigned)weight[m * 8 + g];
                const float   s = scale[m * 8 + g];
                const int   off = (int)(((unsigned)offset[m] >> (4 * g)) & 15u);
                short8 a;
                #pragma unroll
                for (int j = 0; j < 8; ++j) {
                    const int wv = (int)((w >> (4 * j)) & 15u);
                    a[j] = f2bf(s * (float)(wv - off));
                }
                afrag[kh] = a;
            }

            // MFMA: 16 rows x 128 cols = 8 fn-fragments x 2 k-halves
            f32x4 acc[8] = {};
            #pragma unroll
            for (int fn = 0; fn < 8; ++fn) {
                acc[fn] = __builtin_amdgcn_mfma_f32_16x16x32_bf16(
                    afrag[0], bfrag[0][fn], acc[fn], 0, 0, 0);
                acc[fn] = __builtin_amdgcn_mfma_f32_16x16x32_bf16(
                    afrag[1], bfrag[1][fn], acc[fn], 0, 0, 0);
            }

            // Stage 16x128 into padded LDS (2-way bank aliasing = free).
            // C/D layout: col = fn*16 + l15, row16 = l4*4 + j.
            #pragma unroll
            for (int fn = 0; fn < 8; ++fn) {
                const int col = fn * 16 + l15;
                #pragma unroll
                for (int j = 0; j < 4; ++j) {
                    const int row16 = l4 * 4 + j;
                    ws[row16 * 132 + col] = acc[fn][j];
                }
            }
            // wave-internal RAW on LDS (per-wave DS pipe is in-order)
            asm volatile("s_waitcnt lgkmcnt(0)" ::: "memory");

            // Readback + store: each instr = 2 rows x 512B contiguous; rows
            // ascend. Plain stores (R11 win: drain via L2 eviction engine).
            #pragma unroll
            for (int s = 0; s < 8; ++s) {
                const int row16 = s * 2 + (lane >> 5);
                const int c4    = (lane & 31) * 4;
                const f32x4 v = *reinterpret_cast<const f32x4*>(&ws[row16 * 132 + c4]);
                const size_t gr = (size_t)(m0 + fm * 16 + row16);
                *reinterpret_cast<f32x4*>(&C[gr * N_DIM + n0 + c4]) = v;
            }
        }
    }
}

extern "C" void kernel_launch(void* const* d_in, const int* in_sizes, int n_in,
                              void* d_out, int out_size, void* d_ws, size_t ws_size,
                              hipStream_t stream) {
    const float* scale  = (const float*)d_in[0];
    const int*   offset = (const int*)d_in[1];
    const int*   weight = (const int*)d_in[2];
    const float* act    = (const float*)d_in[3];
    float* out  = (float*)d_out;

    gemm_dq<<<512, 256, 0, stream>>>(scale, offset, weight, act, out);
}